// Round 5
// baseline (1946.750 us; speedup 1.0000x reference)
//
#include <hip/hip_runtime.h>

#define NT 256

typedef __attribute__((ext_vector_type(8)))  short bh8;   // 8 bf16
typedef __attribute__((ext_vector_type(16))) float f16v;  // 32x32 acc
typedef __attribute__((ext_vector_type(4)))  float f4v;   // 16x16 acc

// ---- d_ws layout (ushort units) ----
#define WEH_G  0       // expanded sconv weights, hi plane (28672)
#define WEL_G  28672   // lo plane
#define G_WI2H 57344   // isft[p][k], 96 rows stride 72, zero-padded (6912)
#define G_WI2L 64256
#define G_WSH  71168   // scale[k']*sft[k'][p], 48 rows stride 104 (4992)
#define G_WSL  76160   // end 81152 ush = 162304 B

// ---- LDS layout (ushort units): activations only ----
#define SHo  0      // s planes [o][p] stride 104 (6656); overlay: y planes [o][k] stride 72
#define SLo  6656
#define XHo  13312  // x planes [k][c] stride 72 (3456)
#define XLo  16768
#define NU   20224  // 40448 B -> 4 blocks/CU

__device__ __forceinline__ unsigned short f2bf(float f) {  // RNE
  unsigned u = __float_as_uint(f);
  return (unsigned short)((u + 0x7fffu + ((u >> 16) & 1u)) >> 16);
}
__device__ __forceinline__ float bf2f(unsigned short h) {
  return __uint_as_float(((unsigned)h) << 16);
}
__device__ __forceinline__ int lidxf(int k) {  // degree band l/2 for coeff k
  return (k < 1) ? 0 : (k < 6) ? 1 : (k < 15) ? 2 : (k < 28) ? 3 : 4;
}
__device__ __forceinline__ float scale_from_j(int j) {  // sqrt(pi/(4j+1))
  float s = 1.7724539f;
  s = (j == 1) ? 0.79266548f : s;
  s = (j == 2) ? 0.59081795f : s;
  s = (j == 3) ? 0.49159026f : s;
  s = (j >= 4) ? 0.42988324f : s;
  return s;
}
__device__ __forceinline__ float rcp_from_j(int j) {  // 1/scale
  float s = 0.56418958f;
  s = (j == 1) ? 1.2615663f : s;
  s = (j == 2) ? 1.6925688f : s;
  s = (j == 3) ? 2.0342144f : s;
  s = (j >= 4) ? 2.3262120f : s;
  return s;
}
__device__ __forceinline__ bh8 zero8() {
  bh8 z;
#pragma unroll
  for (int e = 0; e < 8; ++e) z[e] = 0;
  return z;
}
// packed split: hi = trunc-bf16 pair via v_perm; lo = trunc(v - bf2f(hi)) pair
__device__ __forceinline__ unsigned pk_hi(float a, float b) {
  return __builtin_amdgcn_perm(__float_as_uint(b), __float_as_uint(a), 0x07060302u);
}
__device__ __forceinline__ void split_store4(unsigned short* dh, unsigned short* dl,
                                             float v0, float v1, float v2, float v3) {
  const unsigned u0 = __float_as_uint(v0), u1 = __float_as_uint(v1);
  const unsigned u2 = __float_as_uint(v2), u3 = __float_as_uint(v3);
  const float d0 = v0 - __uint_as_float(u0 & 0xffff0000u);
  const float d1 = v1 - __uint_as_float(u1 & 0xffff0000u);
  const float d2 = v2 - __uint_as_float(u2 & 0xffff0000u);
  const float d3 = v3 - __uint_as_float(u3 & 0xffff0000u);
  *(uint2*)dh = make_uint2(pk_hi(v0, v1), pk_hi(v2, v3));
  *(uint2*)dl = make_uint2(pk_hi(d0, d1), pk_hi(d2, d3));
}

// ======================= pre-kernel: fill d_ws =======================
__global__ void scnn_prep(const float* __restrict__ sft, const float* __restrict__ isft,
                          const float* __restrict__ w1, const float* __restrict__ w2,
                          const float* __restrict__ w3, const float* __restrict__ w4,
                          const float* __restrict__ w5, const float* __restrict__ w6,
                          unsigned short* __restrict__ wsu) {
  const int gid = blockIdx.x * NT + threadIdx.x;
  const int gstr = gridDim.x * NT;
  const float* wp[6] = {w1, w2, w3, w4, w5, w6};
  const int CIN[6] = {4, 16, 32, 64, 32, 16};
  const int COUT[6] = {16, 32, 64, 32, 16, 4};
  const int CINP[6] = {8, 16, 32, 64, 32, 16};
  const int KP[6] = {64, 96, 160, 320, 160, 96};
  const int R16[6] = {16, 32, 64, 32, 16, 16};
  const int OFF[6] = {0, 1024, 4096, 14336, 24576, 27136};
#pragma unroll
  for (int l = 0; l < 6; ++l) {
    const int cin = CIN[l], cout = COUT[l], cinP = CINP[l], Kp = KP[l];
    const int n = R16[l] * Kp;
    const float* w = wp[l];
    for (int i = gid; i < n; i += gstr) {
      const int o = i / Kp, s = i - o * Kp;
      const int j = s / cinP, c = s - j * cinP;
      float v = 0.f;
      if (o < cout && j < 5 && c < cin) v = w[(o * cin + c) * 5 + j];
      const unsigned short h = f2bf(v);
      wsu[WEH_G + OFF[l] + i] = h;
      wsu[WEL_G + OFF[l] + i] = f2bf(v - bf2f(h));
    }
  }
  for (int i = gid; i < 96 * 72; i += gstr) {  // WI2 = isft[p][k], stride 72
    const int p = i / 72, k = i - p * 72;
    const float v = (p < 90 && k < 45) ? isft[p * 45 + k] : 0.f;
    const unsigned short h = f2bf(v);
    wsu[G_WI2H + i] = h;
    wsu[G_WI2L + i] = f2bf(v - bf2f(h));
  }
  for (int i = gid; i < 48 * 104; i += gstr) {  // WS = scale[k']*sft[k'][p], stride 104
    const int kk = i / 104, p = i - kk * 104;
    float v = 0.f;
    if (kk < 45 && p < 90) v = sft[kk * 90 + p] * scale_from_j(lidxf(kk));
    const unsigned short h = f2bf(v);
    wsu[G_WSH + i] = h;
    wsu[G_WSL + i] = f2bf(v - bf2f(h));
  }
}

// stage2 32-path tile: C[m=p][n=o] += sum_k WI[p][k]*y[o][k], 32x32x16, K=48
__device__ __forceinline__ f16v s2tile(const unsigned short* U,
                                       const unsigned short* __restrict__ wsu,
                                       int mt, int nt, int llo, int lhi) {
  f16v acc;
#pragma unroll
  for (int e = 0; e < 16; ++e) acc[e] = 0.f;
#pragma unroll
  for (int ks = 0; ks < 3; ++ks) {
    const int ao = (mt * 32 + llo) * 72 + ks * 16 + lhi * 8;
    const bh8 ah = *(const bh8*)&wsu[G_WI2H + ao];
    const bh8 al = *(const bh8*)&wsu[G_WI2L + ao];
    const int bo = (nt * 32 + llo) * 72 + ks * 16 + lhi * 8;
    const bh8 bhv = *(const bh8*)&U[SHo + bo];  // y overlay, stride 72
    const bh8 blv = *(const bh8*)&U[SLo + bo];
    acc = __builtin_amdgcn_mfma_f32_32x32x16_bf16(ah, bhv, acc, 0, 0, 0);
    acc = __builtin_amdgcn_mfma_f32_32x32x16_bf16(al, bhv, acc, 0, 0, 0);
    acc = __builtin_amdgcn_mfma_f32_32x32x16_bf16(ah, blv, acc, 0, 0, 0);
  }
  return acc;
}
__device__ __forceinline__ void writes_s(unsigned short* U, f16v acc, int mt,
                                         int nt, int llo, int lhi) {
  const int o = nt * 32 + llo;
#pragma unroll
  for (int g = 0; g < 4; ++g) {
    const int p0 = mt * 32 + g * 8 + lhi * 4;
    split_store4(&U[SHo + o * 104 + p0], &U[SLo + o * 104 + p0],
                 fmaxf(acc[g * 4 + 0], 0.f), fmaxf(acc[g * 4 + 1], 0.f),
                 fmaxf(acc[g * 4 + 2], 0.f), fmaxf(acc[g * 4 + 3], 0.f));
  }
}

// stage2 16-path tile (cout<=16): C[m=p][n=o], 16x16x32, K=64 (y cols 48..63 zeroed)
__device__ __forceinline__ f4v s2tile16(const unsigned short* U,
                                        const unsigned short* __restrict__ wsu,
                                        int mt, int l15, int q4) {
  f4v acc;
  acc[0] = 0.f; acc[1] = 0.f; acc[2] = 0.f; acc[3] = 0.f;
#pragma unroll
  for (int sl = 0; sl < 2; ++sl) {
    const int ao = (mt * 16 + l15) * 72 + sl * 32 + q4 * 8;
    const bh8 ah = *(const bh8*)&wsu[G_WI2H + ao];
    const bh8 al = *(const bh8*)&wsu[G_WI2L + ao];
    const int bo = l15 * 72 + sl * 32 + q4 * 8;
    const bh8 bhv = *(const bh8*)&U[SHo + bo];
    const bh8 blv = *(const bh8*)&U[SLo + bo];
    acc = __builtin_amdgcn_mfma_f32_16x16x32_bf16(ah, bhv, acc, 0, 0, 0);
    acc = __builtin_amdgcn_mfma_f32_16x16x32_bf16(al, bhv, acc, 0, 0, 0);
    acc = __builtin_amdgcn_mfma_f32_16x16x32_bf16(ah, blv, acc, 0, 0, 0);
  }
  return acc;
}
__device__ __forceinline__ void writes_s16(unsigned short* U, f4v acc, int mt,
                                           int l15, int q4) {
  const int o = l15;
  const int p0 = mt * 16 + q4 * 4;
  split_store4(&U[SHo + o * 104 + p0], &U[SLo + o * 104 + p0],
               fmaxf(acc[0], 0.f), fmaxf(acc[1], 0.f),
               fmaxf(acc[2], 0.f), fmaxf(acc[3], 0.f));
}

// ======================= main kernel =======================
__global__ __launch_bounds__(NT, 4)
void scnn_main(const float* __restrict__ xin, const unsigned short* __restrict__ wsu,
               float* __restrict__ out) {
  __shared__ __align__(16) unsigned short U[NU];
  const int tid = threadIdx.x, b = blockIdx.x;
  const int lane = tid & 63, wv = tid >> 6;
  const int llo = lane & 31, lhi = lane >> 5;
  const int l15 = lane & 15, q4 = lane >> 4;

  // ---- stage initial X: [k][c] stride 72, cols 0..7 (cin=4 + pad), scale-folded
  for (int i = tid; i < 384; i += NT) {
    const int k = i >> 3, c = i & 7;
    float v = 0.f;
    if (c < 4 && k < 45) v = xin[(size_t)b * 180 + c * 45 + k] * scale_from_j(lidxf(k));
    const unsigned u = __float_as_uint(v);
    const unsigned short h = (unsigned short)(u >> 16);
    U[XHo + k * 72 + c] = h;
    U[XLo + k * 72 + c] = f2bf(v - bf2f(h));
  }
  __syncthreads();

  for (int layer = 0; layer < 6; ++layer) {
    const int lg   = (layer == 0) ? 3 : (layer == 1) ? 4 : (layer == 2) ? 5
                   : (layer == 3) ? 6 : (layer == 4) ? 5 : 4;  // log2(cinP)
    const int cinP = 1 << lg;
    const int Kp   = (layer == 0) ? 64 : (layer == 1) ? 96 : (layer == 2) ? 160
                   : (layer == 3) ? 320 : (layer == 4) ? 160 : 96;
    const int weoff= (layer == 0) ? 0 : (layer == 1) ? 1024 : (layer == 2) ? 4096
                   : (layer == 3) ? 14336 : (layer == 4) ? 24576 : 27136;
    const int nt16 = (layer == 2) ? 4 : (layer == 1 || layer == 3) ? 2 : 1;
    const int n32  = (layer == 2) ? 2 : 1;
    const bool use16 = (nt16 == 1);  // layers 0,4,5: cout<=16

    // ---- (a) sconv via MFMA, on-the-fly K-expanded A-frags; y [o][k] stride 72
    {
      const int T = 3 * nt16;
      const int hi5 = (5 * cinP + 31) >> 5;
      const int hi4 = (4 * cinP + 31) >> 5;
      const int lo3 = (3 * cinP) >> 5;
      const int lo4 = cinP >> 3;
      for (int t = wv; t < T; t += 4) {
        const int mt = t % 3, nt = t / 3;
        const int k = mt * 16 + l15;
        const int jb = lidxf(k) << lg;
        const int lo = (mt == 0) ? 0 : (mt == 1) ? lo3 : lo4;
        const int hi = (mt == 0) ? hi4 : hi5;
        const unsigned short* wbh = wsu + WEH_G + weoff + (nt * 16 + l15) * Kp + q4 * 8;
        const unsigned short* wbl = wsu + WEL_G + weoff + (nt * 16 + l15) * Kp + q4 * 8;
        f4v acc;
        acc[0] = 0.f; acc[1] = 0.f; acc[2] = 0.f; acc[3] = 0.f;
        for (int st = lo; st < hi; ++st) {
          const int S = st * 32 + q4 * 8;
          const unsigned c0 = (unsigned)(S - jb);
          const int cs = (int)(c0 & 56u);
          bh8 xh = *(const bh8*)&U[XHo + k * 72 + cs];
          bh8 xl = *(const bh8*)&U[XLo + k * 72 + cs];
          if (c0 >= (unsigned)cinP) { xh = zero8(); xl = zero8(); }
          const bh8 wh = *(const bh8*)&wbh[st * 32];
          const bh8 wl = *(const bh8*)&wbl[st * 32];
          acc = __builtin_amdgcn_mfma_f32_16x16x32_bf16(xh, wh, acc, 0, 0, 0);
          acc = __builtin_amdgcn_mfma_f32_16x16x32_bf16(xl, wh, acc, 0, 0, 0);
          acc = __builtin_amdgcn_mfma_f32_16x16x32_bf16(xh, wl, acc, 0, 0, 0);
        }
        // lane holds y[o][kq..kq+3] (C: col=o, rows consecutive k)
        const int o = nt * 16 + l15;
        const int kq = mt * 16 + q4 * 4;
        split_store4(&U[SHo + o * 72 + kq], &U[SLo + o * 72 + kq],
                     acc[0], acc[1], acc[2], acc[3]);
      }
      if (use16) {  // zero y cols 48..63 rows 0..15 (16-path K=64 slice tail)
        for (int i = tid; i < 32; i += NT) {
          const int r = i >> 1, c8 = 48 + (i & 1) * 8;
          *(uint4*)&U[SHo + r * 72 + c8] = make_uint4(0u, 0u, 0u, 0u);
          *(uint4*)&U[SLo + r * 72 + c8] = make_uint4(0u, 0u, 0u, 0u);
        }
      }
      // junk y rows (o >= cout) only feed junk s columns, never read later
    }
    __syncthreads();

    // ---- (b) stage2 MFMA (held in regs across barrier)
    f16v accA32, accB32;
    f4v accA16, accB16;
    bool hasB = false;
    if (use16) {
      hasB = wv < 2;
      accA16 = s2tile16(U, wsu, wv, l15, q4);
      if (hasB) accB16 = s2tile16(U, wsu, wv + 4, l15, q4);
    } else {
      const int T2 = 3 * n32;
      hasB = (wv + 4) < T2;
      if (wv < T2) accA32 = s2tile(U, wsu, wv % 3, wv / 3, llo, lhi);
      if (hasB) accB32 = s2tile(U, wsu, (wv + 4) % 3, (wv + 4) / 3, llo, lhi);
    }
    __syncthreads();

    // ---- (c) relu + split -> s planes [o][p] stride 104 (overwrites y arena)
    if (use16) {
      writes_s16(U, accA16, wv, l15, q4);
      if (hasB) writes_s16(U, accB16, wv + 4, l15, q4);
    } else {
      const int T2 = 3 * n32;
      if (wv < T2) writes_s(U, accA32, wv % 3, wv / 3, llo, lhi);
      if (hasB) writes_s(U, accB32, (wv + 4) % 3, (wv + 4) / 3, llo, lhi);
    }
    __syncthreads();

    // ---- (d) stage3 MFMA, swapped operands: A = s (LDS), B = WS' (global).
    //      C[m=o][n=k']: lane k' fixed, o consecutive -> vector X[k'][o] writes.
    const int T3 = 3 * nt16;
    for (int t = wv; t < T3; t += 4) {
      const int ntK = t % 3, mtO = t / 3;
      f4v acc;
      acc[0] = 0.f; acc[1] = 0.f; acc[2] = 0.f; acc[3] = 0.f;
#pragma unroll
      for (int sl = 0; sl < 3; ++sl) {
        const int ao = (mtO * 16 + l15) * 104 + sl * 32 + q4 * 8;
        const bh8 ah = *(const bh8*)&U[SHo + ao];
        const bh8 al = *(const bh8*)&U[SLo + ao];
        const int bo = (ntK * 16 + l15) * 104 + sl * 32 + q4 * 8;
        const bh8 bhv = *(const bh8*)&wsu[G_WSH + bo];
        const bh8 blv = *(const bh8*)&wsu[G_WSL + bo];
        acc = __builtin_amdgcn_mfma_f32_16x16x32_bf16(ah, bhv, acc, 0, 0, 0);
        acc = __builtin_amdgcn_mfma_f32_16x16x32_bf16(al, bhv, acc, 0, 0, 0);
        acc = __builtin_amdgcn_mfma_f32_16x16x32_bf16(ah, blv, acc, 0, 0, 0);
      }
      const int kk = ntK * 16 + l15;        // k' row (fixed per lane)
      const int oc = mtO * 16 + q4 * 4;     // o columns (consecutive)
      split_store4(&U[XHo + kk * 72 + oc], &U[XLo + kk * 72 + oc],
                   acc[0], acc[1], acc[2], acc[3]);
    }
    __syncthreads();
  }

  // ---- epilogue: out[b][c][k] = (XH+XL)[k][c] * (1/scale[k])
  for (int i = tid; i < 180; i += NT) {
    const int c = i / 45, k = i - c * 45;
    const float v = bf2f(U[XHo + k * 72 + c]) + bf2f(U[XLo + k * 72 + c]);
    out[(size_t)b * 180 + i] = v * rcp_from_j(lidxf(k));
  }
}

extern "C" void kernel_launch(void* const* d_in, const int* in_sizes, int n_in,
                              void* d_out, int out_size, void* d_ws, size_t ws_size,
                              hipStream_t stream) {
  (void)n_in; (void)out_size; (void)ws_size;
  const float* x    = (const float*)d_in[0];
  const float* sft  = (const float*)d_in[1];
  const float* isft = (const float*)d_in[2];
  const float* w1   = (const float*)d_in[3];
  const float* w2   = (const float*)d_in[4];
  const float* w3   = (const float*)d_in[5];
  const float* w4   = (const float*)d_in[6];
  const float* w5   = (const float*)d_in[7];
  const float* w6   = (const float*)d_in[8];
  float* out = (float*)d_out;
  unsigned short* wsu = (unsigned short*)d_ws;  // uses 162304 B of scratch
  const int nb = in_sizes[0] / 180;             // 50000
  scnn_prep<<<32, NT, 0, stream>>>(sft, isft, w1, w2, w3, w4, w5, w6, wsu);
  scnn_main<<<nb, NT, 0, stream>>>(x, wsu, out);
}

// Round 6
// 1527.541 us; speedup vs baseline: 1.2744x; 1.2744x over previous
//
#include <hip/hip_runtime.h>

#define NT 256

typedef __attribute__((ext_vector_type(8)))  short bh8;   // 8 bf16
typedef __attribute__((ext_vector_type(16))) float f16v;  // 32x32 acc
typedef __attribute__((ext_vector_type(4)))  float f4v;   // 16x16 acc

// ---- d_ws layout (ushort units) ----
#define WEH_G  0       // expanded sconv weights, hi plane (28672)
#define WEL_G  28672   // lo plane
#define G_WI2H 57344   // isft[p][k], 96 rows stride 72, zero-padded (6912)
#define G_WI2L 64256
#define G_WSH  71168   // scale[k']*sft[k'][p], 48 rows stride 104 (4992)
#define G_WSL  76160   // end 81152 ush = 162304 B

// ---- LDS layout (ushort units): activations only ----
#define SHo  0      // s planes [o][p] stride 104 (6656); overlay: y planes [o][k] stride 72
#define SLo  6656
#define XHo  13312  // x planes [k][c] stride 72 (3456)
#define XLo  16768
#define NU   20224  // 40448 B -> 4 blocks/CU

__device__ __forceinline__ unsigned short f2bf(float f) {  // RNE
  unsigned u = __float_as_uint(f);
  return (unsigned short)((u + 0x7fffu + ((u >> 16) & 1u)) >> 16);
}
__device__ __forceinline__ float bf2f(unsigned short h) {
  return __uint_as_float(((unsigned)h) << 16);
}
__device__ __forceinline__ int lidxf(int k) {  // degree band l/2 for coeff k
  return (k < 1) ? 0 : (k < 6) ? 1 : (k < 15) ? 2 : (k < 28) ? 3 : 4;
}
__device__ __forceinline__ float scale_from_j(int j) {  // sqrt(pi/(4j+1))
  float s = 1.7724539f;
  s = (j == 1) ? 0.79266548f : s;
  s = (j == 2) ? 0.59081795f : s;
  s = (j == 3) ? 0.49159026f : s;
  s = (j >= 4) ? 0.42988324f : s;
  return s;
}
__device__ __forceinline__ float rcp_from_j(int j) {  // 1/scale
  float s = 0.56418958f;
  s = (j == 1) ? 1.2615663f : s;
  s = (j == 2) ? 1.6925688f : s;
  s = (j == 3) ? 2.0342144f : s;
  s = (j >= 4) ? 2.3262120f : s;
  return s;
}
__device__ __forceinline__ bh8 zero8() {
  bh8 z;
#pragma unroll
  for (int e = 0; e < 8; ++e) z[e] = 0;
  return z;
}
// packed split: hi = trunc-bf16 pair via v_perm; lo = trunc(v - bf2f(hi)) pair
__device__ __forceinline__ unsigned pk_hi(float a, float b) {
  return __builtin_amdgcn_perm(__float_as_uint(b), __float_as_uint(a), 0x07060302u);
}
__device__ __forceinline__ void split_store4(unsigned short* dh, unsigned short* dl,
                                             float v0, float v1, float v2, float v3) {
  const unsigned u0 = __float_as_uint(v0), u1 = __float_as_uint(v1);
  const unsigned u2 = __float_as_uint(v2), u3 = __float_as_uint(v3);
  const float d0 = v0 - __uint_as_float(u0 & 0xffff0000u);
  const float d1 = v1 - __uint_as_float(u1 & 0xffff0000u);
  const float d2 = v2 - __uint_as_float(u2 & 0xffff0000u);
  const float d3 = v3 - __uint_as_float(u3 & 0xffff0000u);
  *(uint2*)dh = make_uint2(pk_hi(v0, v1), pk_hi(v2, v3));
  *(uint2*)dl = make_uint2(pk_hi(d0, d1), pk_hi(d2, d3));
}

// ======================= pre-kernel: fill d_ws =======================
__global__ void scnn_prep(const float* __restrict__ sft, const float* __restrict__ isft,
                          const float* __restrict__ w1, const float* __restrict__ w2,
                          const float* __restrict__ w3, const float* __restrict__ w4,
                          const float* __restrict__ w5, const float* __restrict__ w6,
                          unsigned short* __restrict__ wsu) {
  const int gid = blockIdx.x * NT + threadIdx.x;
  const int gstr = gridDim.x * NT;
  const float* wp[6] = {w1, w2, w3, w4, w5, w6};
  const int CIN[6] = {4, 16, 32, 64, 32, 16};
  const int COUT[6] = {16, 32, 64, 32, 16, 4};
  const int CINP[6] = {8, 16, 32, 64, 32, 16};
  const int KP[6] = {64, 96, 160, 320, 160, 96};
  const int R16[6] = {16, 32, 64, 32, 16, 16};
  const int OFF[6] = {0, 1024, 4096, 14336, 24576, 27136};
#pragma unroll
  for (int l = 0; l < 6; ++l) {
    const int cin = CIN[l], cout = COUT[l], cinP = CINP[l], Kp = KP[l];
    const int n = R16[l] * Kp;
    const float* w = wp[l];
    for (int i = gid; i < n; i += gstr) {
      const int o = i / Kp, s = i - o * Kp;
      const int j = s / cinP, c = s - j * cinP;
      float v = 0.f;
      if (o < cout && j < 5 && c < cin) v = w[(o * cin + c) * 5 + j];
      const unsigned short h = f2bf(v);
      wsu[WEH_G + OFF[l] + i] = h;
      wsu[WEL_G + OFF[l] + i] = f2bf(v - bf2f(h));
    }
  }
  for (int i = gid; i < 96 * 72; i += gstr) {  // WI2 = isft[p][k], stride 72
    const int p = i / 72, k = i - p * 72;
    const float v = (p < 90 && k < 45) ? isft[p * 45 + k] : 0.f;
    const unsigned short h = f2bf(v);
    wsu[G_WI2H + i] = h;
    wsu[G_WI2L + i] = f2bf(v - bf2f(h));
  }
  for (int i = gid; i < 48 * 104; i += gstr) {  // WS = scale[k']*sft[k'][p], stride 104
    const int kk = i / 104, p = i - kk * 104;
    float v = 0.f;
    if (kk < 45 && p < 90) v = sft[kk * 90 + p] * scale_from_j(lidxf(kk));
    const unsigned short h = f2bf(v);
    wsu[G_WSH + i] = h;
    wsu[G_WSL + i] = f2bf(v - bf2f(h));
  }
}

// stage2 32-path tile: C[m=p][n=o] += sum_k WI[p][k]*y[o][k], 32x32x16, K=48
__device__ __forceinline__ f16v s2tile(const unsigned short* U,
                                       const unsigned short* __restrict__ wsu,
                                       int mt, int nt, int llo, int lhi) {
  f16v acc;
#pragma unroll
  for (int e = 0; e < 16; ++e) acc[e] = 0.f;
#pragma unroll
  for (int ks = 0; ks < 3; ++ks) {
    const int ao = (mt * 32 + llo) * 72 + ks * 16 + lhi * 8;
    const bh8 ah = *(const bh8*)&wsu[G_WI2H + ao];
    const bh8 al = *(const bh8*)&wsu[G_WI2L + ao];
    const int bo = (nt * 32 + llo) * 72 + ks * 16 + lhi * 8;
    const bh8 bhv = *(const bh8*)&U[SHo + bo];  // y overlay, stride 72
    const bh8 blv = *(const bh8*)&U[SLo + bo];
    acc = __builtin_amdgcn_mfma_f32_32x32x16_bf16(ah, bhv, acc, 0, 0, 0);
    acc = __builtin_amdgcn_mfma_f32_32x32x16_bf16(al, bhv, acc, 0, 0, 0);
    acc = __builtin_amdgcn_mfma_f32_32x32x16_bf16(ah, blv, acc, 0, 0, 0);
  }
  return acc;
}
__device__ __forceinline__ void writes_s(unsigned short* U, f16v acc, int mt,
                                         int nt, int llo, int lhi) {
  const int o = nt * 32 + llo;
#pragma unroll
  for (int g = 0; g < 4; ++g) {
    const int p0 = mt * 32 + g * 8 + lhi * 4;
    split_store4(&U[SHo + o * 104 + p0], &U[SLo + o * 104 + p0],
                 fmaxf(acc[g * 4 + 0], 0.f), fmaxf(acc[g * 4 + 1], 0.f),
                 fmaxf(acc[g * 4 + 2], 0.f), fmaxf(acc[g * 4 + 3], 0.f));
  }
}

// stage2 16-path tile (cout<=16): C[m=p][n=o], 16x16x32, K=64 (y cols 48..63 zeroed)
__device__ __forceinline__ f4v s2tile16(const unsigned short* U,
                                        const unsigned short* __restrict__ wsu,
                                        int mt, int l15, int q4) {
  f4v acc;
  acc[0] = 0.f; acc[1] = 0.f; acc[2] = 0.f; acc[3] = 0.f;
#pragma unroll
  for (int sl = 0; sl < 2; ++sl) {
    const int ao = (mt * 16 + l15) * 72 + sl * 32 + q4 * 8;
    const bh8 ah = *(const bh8*)&wsu[G_WI2H + ao];
    const bh8 al = *(const bh8*)&wsu[G_WI2L + ao];
    const int bo = l15 * 72 + sl * 32 + q4 * 8;
    const bh8 bhv = *(const bh8*)&U[SHo + bo];
    const bh8 blv = *(const bh8*)&U[SLo + bo];
    acc = __builtin_amdgcn_mfma_f32_16x16x32_bf16(ah, bhv, acc, 0, 0, 0);
    acc = __builtin_amdgcn_mfma_f32_16x16x32_bf16(al, bhv, acc, 0, 0, 0);
    acc = __builtin_amdgcn_mfma_f32_16x16x32_bf16(ah, blv, acc, 0, 0, 0);
  }
  return acc;
}
__device__ __forceinline__ void writes_s16(unsigned short* U, f4v acc, int mt,
                                           int l15, int q4) {
  const int o = l15;
  const int p0 = mt * 16 + q4 * 4;
  split_store4(&U[SHo + o * 104 + p0], &U[SLo + o * 104 + p0],
               fmaxf(acc[0], 0.f), fmaxf(acc[1], 0.f),
               fmaxf(acc[2], 0.f), fmaxf(acc[3], 0.f));
}

// ======================= per-layer body (compile-time specialized) =======
template <int layer>
__device__ __forceinline__ void layer_body(unsigned short* U,
                                           const unsigned short* __restrict__ wsu,
                                           int tid, int wv, int llo, int lhi,
                                           int l15, int q4) {
  constexpr int lg   = (layer == 0) ? 3 : (layer == 1) ? 4 : (layer == 2) ? 5
                     : (layer == 3) ? 6 : (layer == 4) ? 5 : 4;  // log2(cinP)
  constexpr int cinP = 1 << lg;
  constexpr int Kp   = (layer == 0) ? 64 : (layer == 1) ? 96 : (layer == 2) ? 160
                     : (layer == 3) ? 320 : (layer == 4) ? 160 : 96;
  constexpr int weoff= (layer == 0) ? 0 : (layer == 1) ? 1024 : (layer == 2) ? 4096
                     : (layer == 3) ? 14336 : (layer == 4) ? 24576 : 27136;
  constexpr int nt16 = (layer == 2) ? 4 : (layer == 1 || layer == 3) ? 2 : 1;
  constexpr int n32  = (layer == 2) ? 2 : 1;
  constexpr bool use16 = (nt16 == 1);  // layers 0,4,5: cout<=16

  // ---- (a) sconv via MFMA, on-the-fly K-expanded A-frags; y [o][k] stride 72
  {
    constexpr int T = 3 * nt16;
    constexpr int hi5 = (5 * cinP + 31) >> 5;
    constexpr int hi4 = (4 * cinP + 31) >> 5;
    constexpr int lo3 = (3 * cinP) >> 5;
    constexpr int lo4 = cinP >> 3;
    for (int t = wv; t < T; t += 4) {
      const int mt = t % 3, nt = t / 3;
      const int k = mt * 16 + l15;
      const int jb = lidxf(k) << lg;
      const int lo = (mt == 0) ? 0 : (mt == 1) ? lo3 : lo4;
      const int hi = (mt == 0) ? hi4 : hi5;
      const unsigned short* wbh = wsu + WEH_G + weoff + (nt * 16 + l15) * Kp + q4 * 8;
      const unsigned short* wbl = wsu + WEL_G + weoff + (nt * 16 + l15) * Kp + q4 * 8;
      f4v acc;
      acc[0] = 0.f; acc[1] = 0.f; acc[2] = 0.f; acc[3] = 0.f;
      for (int st = lo; st < hi; ++st) {
        const int S = st * 32 + q4 * 8;
        const unsigned c0 = (unsigned)(S - jb);
        const int cs = (int)(c0 & 56u);
        bh8 xh = *(const bh8*)&U[XHo + k * 72 + cs];
        bh8 xl = *(const bh8*)&U[XLo + k * 72 + cs];
        if (c0 >= (unsigned)cinP) { xh = zero8(); xl = zero8(); }
        const bh8 wh = *(const bh8*)&wbh[st * 32];
        const bh8 wl = *(const bh8*)&wbl[st * 32];
        acc = __builtin_amdgcn_mfma_f32_16x16x32_bf16(xh, wh, acc, 0, 0, 0);
        acc = __builtin_amdgcn_mfma_f32_16x16x32_bf16(xl, wh, acc, 0, 0, 0);
        acc = __builtin_amdgcn_mfma_f32_16x16x32_bf16(xh, wl, acc, 0, 0, 0);
      }
      // lane holds y[o][kq..kq+3] (C: col=o, rows consecutive k)
      const int o = nt * 16 + l15;
      const int kq = mt * 16 + q4 * 4;
      split_store4(&U[SHo + o * 72 + kq], &U[SLo + o * 72 + kq],
                   acc[0], acc[1], acc[2], acc[3]);
    }
    if (use16) {  // zero y cols 48..63 rows 0..15 (16-path K=64 slice tail)
      for (int i = tid; i < 32; i += NT) {
        const int r = i >> 1, c8 = 48 + (i & 1) * 8;
        *(uint4*)&U[SHo + r * 72 + c8] = make_uint4(0u, 0u, 0u, 0u);
        *(uint4*)&U[SLo + r * 72 + c8] = make_uint4(0u, 0u, 0u, 0u);
      }
    }
    // rows o >= cout: expanded weights are zero there -> y rows are zero (benign)
  }
  __syncthreads();

  // ---- (b)+(c) stage2 MFMA, acc in regs across barrier; exactly ONE
  //      accumulator type instantiated per layer (no cross-path union/spill)
  if constexpr (use16) {
    const bool hb = wv < 2;
    f4v a0 = s2tile16(U, wsu, wv, l15, q4);
    f4v a1;
    if (hb) a1 = s2tile16(U, wsu, wv + 4, l15, q4);
    __syncthreads();
    writes_s16(U, a0, wv, l15, q4);
    if (hb) writes_s16(U, a1, wv + 4, l15, q4);
  } else {
    constexpr int T2 = 3 * n32;
    const bool hA = wv < T2, hB = (wv + 4) < T2;
    f16v a0, a1;
    if (hA) a0 = s2tile(U, wsu, wv % 3, wv / 3, llo, lhi);
    if (hB) a1 = s2tile(U, wsu, (wv + 4) % 3, (wv + 4) / 3, llo, lhi);
    __syncthreads();
    if (hA) writes_s(U, a0, wv % 3, wv / 3, llo, lhi);
    if (hB) writes_s(U, a1, (wv + 4) % 3, (wv + 4) / 3, llo, lhi);
  }
  __syncthreads();

  // ---- (d) stage3 MFMA, swapped operands: A = s (LDS), B = WS' (global).
  //      C[m=o][n=k']: lane k' fixed, o consecutive -> vector X[k'][o] writes.
  constexpr int T3 = 3 * nt16;
  for (int t = wv; t < T3; t += 4) {
    const int ntK = t % 3, mtO = t / 3;
    f4v acc;
    acc[0] = 0.f; acc[1] = 0.f; acc[2] = 0.f; acc[3] = 0.f;
#pragma unroll
    for (int sl = 0; sl < 3; ++sl) {
      const int ao = (mtO * 16 + l15) * 104 + sl * 32 + q4 * 8;
      const bh8 ah = *(const bh8*)&U[SHo + ao];
      const bh8 al = *(const bh8*)&U[SLo + ao];
      const int bo = (ntK * 16 + l15) * 104 + sl * 32 + q4 * 8;
      const bh8 bhv = *(const bh8*)&wsu[G_WSH + bo];
      const bh8 blv = *(const bh8*)&wsu[G_WSL + bo];
      acc = __builtin_amdgcn_mfma_f32_16x16x32_bf16(ah, bhv, acc, 0, 0, 0);
      acc = __builtin_amdgcn_mfma_f32_16x16x32_bf16(al, bhv, acc, 0, 0, 0);
      acc = __builtin_amdgcn_mfma_f32_16x16x32_bf16(ah, blv, acc, 0, 0, 0);
    }
    const int kk = ntK * 16 + l15;     // k' row (fixed per lane)
    const int oc = mtO * 16 + q4 * 4;  // o columns (consecutive)
    split_store4(&U[XHo + kk * 72 + oc], &U[XLo + kk * 72 + oc],
                 acc[0], acc[1], acc[2], acc[3]);
  }
  __syncthreads();
}

// ======================= main kernel =======================
__global__ __launch_bounds__(NT, 4)
void scnn_main(const float* __restrict__ xin, const unsigned short* __restrict__ wsu,
               float* __restrict__ out) {
  __shared__ __align__(16) unsigned short U[NU];
  const int tid = threadIdx.x, b = blockIdx.x;
  const int lane = tid & 63, wv = tid >> 6;
  const int llo = lane & 31, lhi = lane >> 5;
  const int l15 = lane & 15, q4 = lane >> 4;

  // ---- stage initial X: [k][c] stride 72, cols 0..7 (cin=4 + pad), scale-folded
  for (int i = tid; i < 384; i += NT) {
    const int k = i >> 3, c = i & 7;
    float v = 0.f;
    if (c < 4 && k < 45) v = xin[(size_t)b * 180 + c * 45 + k] * scale_from_j(lidxf(k));
    const unsigned u = __float_as_uint(v);
    const unsigned short h = (unsigned short)(u >> 16);
    U[XHo + k * 72 + c] = h;
    U[XLo + k * 72 + c] = f2bf(v - bf2f(h));
  }
  __syncthreads();

  layer_body<0>(U, wsu, tid, wv, llo, lhi, l15, q4);
  layer_body<1>(U, wsu, tid, wv, llo, lhi, l15, q4);
  layer_body<2>(U, wsu, tid, wv, llo, lhi, l15, q4);
  layer_body<3>(U, wsu, tid, wv, llo, lhi, l15, q4);
  layer_body<4>(U, wsu, tid, wv, llo, lhi, l15, q4);
  layer_body<5>(U, wsu, tid, wv, llo, lhi, l15, q4);

  // ---- epilogue: out[b][c][k] = (XH+XL)[k][c] * (1/scale[k])
  for (int i = tid; i < 180; i += NT) {
    const int c = i / 45, k = i - c * 45;
    const float v = bf2f(U[XHo + k * 72 + c]) + bf2f(U[XLo + k * 72 + c]);
    out[(size_t)b * 180 + i] = v * rcp_from_j(lidxf(k));
  }
}

extern "C" void kernel_launch(void* const* d_in, const int* in_sizes, int n_in,
                              void* d_out, int out_size, void* d_ws, size_t ws_size,
                              hipStream_t stream) {
  (void)n_in; (void)out_size; (void)ws_size;
  const float* x    = (const float*)d_in[0];
  const float* sft  = (const float*)d_in[1];
  const float* isft = (const float*)d_in[2];
  const float* w1   = (const float*)d_in[3];
  const float* w2   = (const float*)d_in[4];
  const float* w3   = (const float*)d_in[5];
  const float* w4   = (const float*)d_in[6];
  const float* w5   = (const float*)d_in[7];
  const float* w6   = (const float*)d_in[8];
  float* out = (float*)d_out;
  unsigned short* wsu = (unsigned short*)d_ws;  // uses 162304 B of scratch
  const int nb = in_sizes[0] / 180;             // 50000
  scnn_prep<<<32, NT, 0, stream>>>(sft, isft, w1, w2, w3, w4, w5, w6, wsu);
  scnn_main<<<nb, NT, 0, stream>>>(x, wsu, out);
}

// Round 8
// 1143.113 us; speedup vs baseline: 1.7030x; 1.3363x over previous
//
#include <hip/hip_runtime.h>

#define NT 256

typedef __attribute__((ext_vector_type(8)))  short bh8;   // 8 bf16
typedef __attribute__((ext_vector_type(16))) float f16v;  // 32x32 acc
typedef __attribute__((ext_vector_type(4)))  float f4v;   // 16x16 acc

// ---- d_ws layout (ushort units): pre-swizzled 64-lane x 16B fragment dumps.
// Every frag is 512 ush (1KB); a wave loads it as base + lane*8 (fully coalesced).
// Total footprint 75776 ush = 151552 B (<= 156160 B proven safe in r3).
#define FW_H    0      // sconv expanded-weight B-frags, 56 frags (28672)
#define FW_L    28672
#define W2A32_H 57344  // stage2 32x32 A-frags (isft), 9 frags (4608)
#define W2A32_L 61952
#define W3B_H   66560  // stage3 B-frags (scale*sft), 9 frags (4608)
#define W3B_L   71168  // end 75776 ush = 151552 B

// ---- LDS layout (ushort units): activations only ----
#define SHo  0      // s planes [o][p] stride 104 (6656); overlay: y planes [o][k] stride 72
#define SLo  6656
#define XHo  13312  // x planes [k][c] stride 72 (3456)
#define XLo  16768
#define ZOFF 20224  // 8-ush zero block for OOB sconv A-frag reads
#define NU   20232  // 40464 B -> 4 blocks/CU

__device__ __forceinline__ unsigned short f2bf(float f) {  // RNE
  unsigned u = __float_as_uint(f);
  return (unsigned short)((u + 0x7fffu + ((u >> 16) & 1u)) >> 16);
}
__device__ __forceinline__ float bf2f(unsigned short h) {
  return __uint_as_float(((unsigned)h) << 16);
}
__device__ __forceinline__ int lidxf(int k) {  // degree band l/2 for coeff k
  return (k < 1) ? 0 : (k < 6) ? 1 : (k < 15) ? 2 : (k < 28) ? 3 : 4;
}
__device__ __forceinline__ float scale_from_j(int j) {  // sqrt(pi/(4j+1))
  float s = 1.7724539f;
  s = (j == 1) ? 0.79266548f : s;
  s = (j == 2) ? 0.59081795f : s;
  s = (j == 3) ? 0.49159026f : s;
  s = (j >= 4) ? 0.42988324f : s;
  return s;
}
__device__ __forceinline__ float rcp_from_j(int j) {  // 1/scale
  float s = 0.56418958f;
  s = (j == 1) ? 1.2615663f : s;
  s = (j == 2) ? 1.6925688f : s;
  s = (j == 3) ? 2.0342144f : s;
  s = (j >= 4) ? 2.3262120f : s;
  return s;
}
// packed split: hi = trunc-bf16 pair via v_perm; lo = trunc(v - bf2f(hi)) pair
__device__ __forceinline__ unsigned pk_hi(float a, float b) {
  return __builtin_amdgcn_perm(__float_as_uint(b), __float_as_uint(a), 0x07060302u);
}
__device__ __forceinline__ void split_store4(unsigned short* dh, unsigned short* dl,
                                             float v0, float v1, float v2, float v3) {
  const unsigned u0 = __float_as_uint(v0), u1 = __float_as_uint(v1);
  const unsigned u2 = __float_as_uint(v2), u3 = __float_as_uint(v3);
  const float d0 = v0 - __uint_as_float(u0 & 0xffff0000u);
  const float d1 = v1 - __uint_as_float(u1 & 0xffff0000u);
  const float d2 = v2 - __uint_as_float(u2 & 0xffff0000u);
  const float d3 = v3 - __uint_as_float(u3 & 0xffff0000u);
  *(uint2*)dh = make_uint2(pk_hi(v0, v1), pk_hi(v2, v3));
  *(uint2*)dl = make_uint2(pk_hi(d0, d1), pk_hi(d2, d3));
}

// ======================= pre-kernel: build fragment dumps =======================
__global__ void scnn_prep(const float* __restrict__ sft, const float* __restrict__ isft,
                          const float* __restrict__ w1, const float* __restrict__ w2,
                          const float* __restrict__ w3, const float* __restrict__ w4,
                          const float* __restrict__ w5, const float* __restrict__ w6,
                          unsigned short* __restrict__ wsu) {
  const int gid = blockIdx.x * NT + threadIdx.x;
  const int gstr = gridDim.x * NT;
  const float* wp[6] = {w1, w2, w3, w4, w5, w6};
  const int CIN[6] = {4, 16, 32, 64, 32, 16};
  const int COUT[6] = {16, 32, 64, 32, 16, 4};
  const int LG[6] = {3, 4, 5, 6, 5, 4};
  const int NST[6] = {2, 3, 5, 10, 5, 3};
  const int NTC[6] = {1, 2, 4, 2, 1, 1};
  const int FOFF[6] = {0, 2, 8, 28, 48, 53};
#pragma unroll
  for (int l = 0; l < 6; ++l) {
    const int cin = CIN[l], cout = COUT[l], lg = LG[l], cinP = 1 << lg;
    const int nst = NST[l];
    const int n = NTC[l] * nst * 512;
    const float* w = wp[l];
    const int base = FOFF[l] * 512;
    for (int i = gid; i < n; i += gstr) {
      const int fid = i >> 9, lane = (i >> 3) & 63, e = i & 7;
      const int nt = fid / nst, st = fid - nt * nst;
      const int o = nt * 16 + (lane & 15);
      const int s = st * 32 + (lane >> 4) * 8 + e;
      const int j = s >> lg, c = s & (cinP - 1);
      float v = 0.f;
      if (o < cout && j < 5 && c < cin) v = w[(o * cin + c) * 5 + j];
      const unsigned short h = f2bf(v);
      wsu[FW_H + base + i] = h;
      wsu[FW_L + base + i] = f2bf(v - bf2f(h));
    }
  }
  for (int i = gid; i < 9 * 512; i += gstr) {  // stage2 32x32 A-frags (isft)
    const int fid = i >> 9, lane = (i >> 3) & 63, e = i & 7;
    const int mt = fid / 3, ks = fid - mt * 3;
    const int p = mt * 32 + (lane & 31);
    const int k = ks * 16 + (lane >> 5) * 8 + e;
    const float v = (p < 90 && k < 45) ? isft[p * 45 + k] : 0.f;
    const unsigned short h = f2bf(v);
    wsu[W2A32_H + i] = h;
    wsu[W2A32_L + i] = f2bf(v - bf2f(h));
  }
  for (int i = gid; i < 9 * 512; i += gstr) {  // stage3 B-frags (scale*sft)
    const int fid = i >> 9, lane = (i >> 3) & 63, e = i & 7;
    const int ntK = fid / 3, sl = fid - ntK * 3;
    const int kk = ntK * 16 + (lane & 15);
    const int p = sl * 32 + (lane >> 4) * 8 + e;
    float v = 0.f;
    if (kk < 45 && p < 90) v = sft[kk * 90 + p] * scale_from_j(lidxf(kk));
    const unsigned short h = f2bf(v);
    wsu[W3B_H + i] = h;
    wsu[W3B_L + i] = f2bf(v - bf2f(h));
  }
}

// stage2 tile: C[m=p][n=o] += sum_k WI[p][k]*y[o][k], 32x32x16, K=48.
// Junk y rows (o >= cout) feed only never-read s columns; K=48 never touches
// the k>=48 junk region. A-frags coalesced from global frag dump.
__device__ __forceinline__ f16v s2tile(const unsigned short* U,
                                       const unsigned short* __restrict__ wsu,
                                       int mt, int nt, int llo, int lhi, int lof) {
  f16v a1, a2;
#pragma unroll
  for (int e = 0; e < 16; ++e) { a1[e] = 0.f; a2[e] = 0.f; }
  const unsigned short* fh = wsu + W2A32_H + mt * 3 * 512 + lof;
#pragma unroll
  for (int ks = 0; ks < 3; ++ks) {
    const bh8 ah = *(const bh8*)&fh[ks * 512];
    const bh8 al = *(const bh8*)&fh[(W2A32_L - W2A32_H) + ks * 512];
    const int bo = (nt * 32 + llo) * 72 + ks * 16 + lhi * 8;
    const bh8 bhv = *(const bh8*)&U[SHo + bo];  // y overlay, stride 72
    const bh8 blv = *(const bh8*)&U[SLo + bo];
    a1 = __builtin_amdgcn_mfma_f32_32x32x16_bf16(ah, bhv, a1, 0, 0, 0);
    a2 = __builtin_amdgcn_mfma_f32_32x32x16_bf16(al, bhv, a2, 0, 0, 0);
    a2 = __builtin_amdgcn_mfma_f32_32x32x16_bf16(ah, blv, a2, 0, 0, 0);
  }
  return a1 + a2;
}
__device__ __forceinline__ void writes_s(unsigned short* U, f16v acc, int mt,
                                         int nt, int llo, int lhi) {
  const int o = nt * 32 + llo;
#pragma unroll
  for (int g = 0; g < 4; ++g) {
    const int p0 = mt * 32 + g * 8 + lhi * 4;
    split_store4(&U[SHo + o * 104 + p0], &U[SLo + o * 104 + p0],
                 fmaxf(acc[g * 4 + 0], 0.f), fmaxf(acc[g * 4 + 1], 0.f),
                 fmaxf(acc[g * 4 + 2], 0.f), fmaxf(acc[g * 4 + 3], 0.f));
  }
}

// ======================= per-layer body (compile-time specialized) =======
template <int layer>
__device__ __forceinline__ void layer_body(unsigned short* U,
                                           const unsigned short* __restrict__ wsu,
                                           int tid, int wv, int llo, int lhi,
                                           int l15, int q4, int lof) {
  constexpr int lg   = (layer == 0) ? 3 : (layer == 1) ? 4 : (layer == 2) ? 5
                     : (layer == 3) ? 6 : (layer == 4) ? 5 : 4;  // log2(cinP)
  constexpr int cinP = 1 << lg;
  constexpr int NSTc = (layer == 0) ? 2 : (layer == 1) ? 3 : (layer == 2) ? 5
                     : (layer == 3) ? 10 : (layer == 4) ? 5 : 3;
  constexpr int FOFFc= (layer == 0) ? 0 : (layer == 1) ? 2 : (layer == 2) ? 8
                     : (layer == 3) ? 28 : (layer == 4) ? 48 : 53;
  constexpr int nt16 = (layer == 2) ? 4 : (layer == 1 || layer == 3) ? 2 : 1;
  constexpr int n32  = (layer == 2) ? 2 : 1;

  // ---- (a) sconv via MFMA, pre-swizzled weight frags; y [o][k] stride 72
  {
    constexpr int T = 3 * nt16;
    constexpr int hi5 = (5 * cinP + 31) >> 5;
    constexpr int hi4 = (4 * cinP + 31) >> 5;
    constexpr int lo3 = (3 * cinP) >> 5;
    constexpr int lo4 = cinP >> 3;
    for (int t = wv; t < T; t += 4) {
      const int mt = t % 3, nt = t / 3;
      const int k = mt * 16 + l15;
      const int jb = lidxf(k) << lg;
      const int lo = (mt == 0) ? 0 : (mt == 1) ? lo3 : lo4;
      const int hi = (mt == 0) ? hi4 : hi5;
      const unsigned short* wfh = wsu + FW_H + (FOFFc + nt * NSTc) * 512 + lof;
      f4v a1, a2;
      a1[0] = a1[1] = a1[2] = a1[3] = 0.f;
      a2[0] = a2[1] = a2[2] = a2[3] = 0.f;
      for (int st = lo; st < hi; ++st) {
        const int S = st * 32 + q4 * 8;
        const unsigned c0 = (unsigned)(S - jb);
        const int base = XHo + k * 72 + (int)(c0 & 56u);
        const bool oob = c0 >= (unsigned)cinP;
        const int axh = oob ? ZOFF : base;
        const int axl = oob ? ZOFF : (base + (XLo - XHo));
        const bh8 xh = *(const bh8*)&U[axh];
        const bh8 xl = *(const bh8*)&U[axl];
        const bh8 wh = *(const bh8*)&wfh[st * 512];
        const bh8 wl = *(const bh8*)&wfh[(FW_L - FW_H) + st * 512];
        a1 = __builtin_amdgcn_mfma_f32_16x16x32_bf16(xh, wh, a1, 0, 0, 0);
        a2 = __builtin_amdgcn_mfma_f32_16x16x32_bf16(xl, wh, a2, 0, 0, 0);
        a2 = __builtin_amdgcn_mfma_f32_16x16x32_bf16(xh, wl, a2, 0, 0, 0);
      }
      const f4v acc = a1 + a2;
      // lane holds y[o][kq..kq+3] (C: col=o, rows consecutive k)
      const int o = nt * 16 + l15;
      const int kq = mt * 16 + q4 * 4;
      split_store4(&U[SHo + o * 72 + kq], &U[SLo + o * 72 + kq],
                   acc[0], acc[1], acc[2], acc[3]);
    }
  }
  __syncthreads();

  // ---- (b)+(c) stage2 MFMA (32-path for ALL layers), acc in regs across barrier
  {
    constexpr int T2 = 3 * n32;
    const bool hA = wv < T2, hB = (wv + 4) < T2;
    f16v a0, a1;
    if (hA) a0 = s2tile(U, wsu, wv % 3, wv / 3, llo, lhi, lof);
    if (hB) a1 = s2tile(U, wsu, (wv + 4) % 3, (wv + 4) / 3, llo, lhi, lof);
    __syncthreads();
    if (hA) writes_s(U, a0, wv % 3, wv / 3, llo, lhi);
    if (hB) writes_s(U, a1, (wv + 4) % 3, (wv + 4) / 3, llo, lhi);
  }
  __syncthreads();

  // ---- (d) stage3 MFMA: A = s (LDS), B = WS' frags (global).
  //      C[m=o][n=k']: lane k' fixed, o consecutive -> vector X[k'][o] writes.
  constexpr int T3 = 3 * nt16;
  for (int t = wv; t < T3; t += 4) {
    const int ntK = t % 3, mtO = t / 3;
    const unsigned short* fb = wsu + W3B_H + ntK * 3 * 512 + lof;
    f4v a1, a2;
    a1[0] = a1[1] = a1[2] = a1[3] = 0.f;
    a2[0] = a2[1] = a2[2] = a2[3] = 0.f;
#pragma unroll
    for (int sl = 0; sl < 3; ++sl) {
      const int ao = (mtO * 16 + l15) * 104 + sl * 32 + q4 * 8;
      const bh8 ah = *(const bh8*)&U[SHo + ao];
      const bh8 al = *(const bh8*)&U[SLo + ao];
      const bh8 bhv = *(const bh8*)&fb[sl * 512];
      const bh8 blv = *(const bh8*)&fb[(W3B_L - W3B_H) + sl * 512];
      a1 = __builtin_amdgcn_mfma_f32_16x16x32_bf16(ah, bhv, a1, 0, 0, 0);
      a2 = __builtin_amdgcn_mfma_f32_16x16x32_bf16(al, bhv, a2, 0, 0, 0);
      a2 = __builtin_amdgcn_mfma_f32_16x16x32_bf16(ah, blv, a2, 0, 0, 0);
    }
    const f4v acc = a1 + a2;
    const int kk = ntK * 16 + l15;     // k' row (fixed per lane)
    const int oc = mtO * 16 + q4 * 4;  // o columns (consecutive)
    split_store4(&U[XHo + kk * 72 + oc], &U[XLo + kk * 72 + oc],
                 acc[0], acc[1], acc[2], acc[3]);
  }
  __syncthreads();
}

// ======================= main kernel =======================
__global__ __launch_bounds__(NT, 4)
void scnn_main(const float* __restrict__ xin, const unsigned short* __restrict__ wsu,
               float* __restrict__ out) {
  __shared__ __align__(16) unsigned short U[NU];
  const int tid = threadIdx.x, b = blockIdx.x;
  const int lane = tid & 63, wv = tid >> 6;
  const int llo = lane & 31, lhi = lane >> 5;
  const int l15 = lane & 15, q4 = lane >> 4;
  const int lof = lane << 3;

  // ---- stage initial X: [k][c] stride 72, cols 0..7 (cin=4 + pad), scale-folded
  for (int i = tid; i < 384; i += NT) {
    const int k = i >> 3, c = i & 7;
    float v = 0.f;
    if (c < 4 && k < 45) v = xin[(size_t)b * 180 + c * 45 + k] * scale_from_j(lidxf(k));
    const unsigned u = __float_as_uint(v);
    const unsigned short h = (unsigned short)(u >> 16);
    U[XHo + k * 72 + c] = h;
    U[XLo + k * 72 + c] = f2bf(v - bf2f(h));
  }
  if (tid < 8) U[ZOFF + tid] = 0;  // zero block for OOB A-frag reads
  __syncthreads();

  layer_body<0>(U, wsu, tid, wv, llo, lhi, l15, q4, lof);
  layer_body<1>(U, wsu, tid, wv, llo, lhi, l15, q4, lof);
  layer_body<2>(U, wsu, tid, wv, llo, lhi, l15, q4, lof);
  layer_body<3>(U, wsu, tid, wv, llo, lhi, l15, q4, lof);
  layer_body<4>(U, wsu, tid, wv, llo, lhi, l15, q4, lof);
  layer_body<5>(U, wsu, tid, wv, llo, lhi, l15, q4, lof);

  // ---- epilogue: out[b][c][k] = (XH+XL)[k][c] * (1/scale[k])
  for (int i = tid; i < 180; i += NT) {
    const int c = i / 45, k = i - c * 45;
    const float v = bf2f(U[XHo + k * 72 + c]) + bf2f(U[XLo + k * 72 + c]);
    out[(size_t)b * 180 + i] = v * rcp_from_j(lidxf(k));
  }
}

extern "C" void kernel_launch(void* const* d_in, const int* in_sizes, int n_in,
                              void* d_out, int out_size, void* d_ws, size_t ws_size,
                              hipStream_t stream) {
  (void)n_in; (void)out_size; (void)ws_size;
  const float* x    = (const float*)d_in[0];
  const float* sft  = (const float*)d_in[1];
  const float* isft = (const float*)d_in[2];
  const float* w1   = (const float*)d_in[3];
  const float* w2   = (const float*)d_in[4];
  const float* w3   = (const float*)d_in[5];
  const float* w4   = (const float*)d_in[6];
  const float* w5   = (const float*)d_in[7];
  const float* w6   = (const float*)d_in[8];
  float* out = (float*)d_out;
  unsigned short* wsu = (unsigned short*)d_ws;  // uses 151552 B of scratch
  const int nb = in_sizes[0] / 180;             // 50000
  scnn_prep<<<64, NT, 0, stream>>>(sft, isft, w1, w2, w3, w4, w5, w6, wsu);
  scnn_main<<<nb, NT, 0, stream>>>(x, wsu, out);
}